// Round 8
// baseline (324.751 us; speedup 1.0000x reference)
//
#include <hip/hip_runtime.h>
#include <math.h>

#define Nq 2048
#define Bq 8
#define Kq 4
#define NE 8    // elements per lane (2048 / (4 waves * 64 lanes))
#define SEG 512 // elements per wave segment
#define TWO_PI_D 6.283185307179586
#define PI_D 3.141592653589793
#define INV2PI_D 0.15915494309189535

// ---------------- wave helpers ----------------

__device__ __forceinline__ double wave_sum_d(double v) {
#pragma unroll
  for (int off = 1; off < 64; off <<= 1) v += __shfl_xor(v, off, 64);
  return v;
}

// Canonical GCN DPP wave64 sum; uniform result via readlane 63.
__device__ __forceinline__ float dpp_sum_f32(float v) {
  v += __int_as_float(__builtin_amdgcn_update_dpp(0, __float_as_int(v), 0x111, 0xf, 0xf, false));
  v += __int_as_float(__builtin_amdgcn_update_dpp(0, __float_as_int(v), 0x112, 0xf, 0xf, false));
  v += __int_as_float(__builtin_amdgcn_update_dpp(0, __float_as_int(v), 0x114, 0xf, 0xe, false));
  v += __int_as_float(__builtin_amdgcn_update_dpp(0, __float_as_int(v), 0x118, 0xf, 0xc, false));
  v += __int_as_float(__builtin_amdgcn_update_dpp(0, __float_as_int(v), 0x142, 0xa, 0xf, false));
  v += __int_as_float(__builtin_amdgcn_update_dpp(0, __float_as_int(v), 0x143, 0xc, 0xf, false));
  return __int_as_float(__builtin_amdgcn_readlane(__float_as_int(v), 63));
}

__device__ __forceinline__ float dpp_up1(float v) {  // lane i <- lane i-1
  return __int_as_float(__builtin_amdgcn_update_dpp(0, __float_as_int(v), 0x138, 0xf, 0xf, false));
}
__device__ __forceinline__ float dpp_dn1(float v) {  // lane i <- lane i+1
  return __int_as_float(__builtin_amdgcn_update_dpp(0, __float_as_int(v), 0x130, 0xf, 0xf, false));
}

__device__ __forceinline__ double lane_excl_prefix_d(double T, int lane) {
  double acc = T;
#pragma unroll
  for (int off = 1; off < 64; off <<= 1) {
    double t = __shfl_up(acc, off, 64);
    if (lane >= off) acc += t;
  }
  return acc - T;
}

__device__ __forceinline__ void fast_sincos_ph(double ph, float* sn, float* cs) {
  double k = trunc(ph * INV2PI_D);
  float phr = (float)(ph - k * TWO_PI_D);
  __sincosf(phr, sn, cs);
}

// Ap = (coef*opedoub + diag) p over a 512-row segment, NE=8 per lane.
// dd[e] must already include +6*coef. hL/hR = cross-wave p halos.
template <bool UNIT>
__device__ __forceinline__ void applyA8(const float* p, float* Ap,
                                        const float* dd, float ddu, float c,
                                        float c3, float c4, float hL0, float hL1,
                                        float hR0, float hR1, int lane,
                                        bool isF, bool isL) {
  float lm1 = dpp_up1(p[NE - 1]);
  float lm2 = dpp_up1(p[NE - 2]);
  float rp1 = dpp_dn1(p[0]);
  float rp2 = dpp_dn1(p[1]);
  if (lane == 0) { lm2 = hL0; lm1 = hL1; }
  if (lane == 63) { rp1 = hR0; rp2 = hR1; }
#pragma unroll
  for (int e = 0; e < NE; ++e) {
    float m2 = (e >= 2) ? p[e - 2] : (e == 1 ? lm1 : lm2);
    float m1 = (e >= 1) ? p[e - 1] : lm1;
    float q1 = (e <= NE - 2) ? p[e + 1] : rp1;
    float q2 = (e <= NE - 3) ? p[e + 2] : (e == NE - 2 ? rp1 : rp2);
    float u = fmaf(c, m2 + q2, -(c4 * (m1 + q1)));
    Ap[e] = fmaf(UNIT ? ddu : dd[e], p[e], u);
  }
  if (isF && lane == 0) {  // global rows 0,1
    float d0 = (UNIT ? ddu : dd[0]) - c4;
    Ap[0] = fmaf(d0, p[0], fmaf(c, p[2], -(c3 * p[1])));
    float d1 = UNIT ? ddu : dd[1];
    Ap[1] = fmaf(d1, p[1], -(c3 * p[0])) + fmaf(c, p[3], -(c4 * p[2]));
  }
  if (isL && lane == 63) {  // global rows N-2, N-1
    float dm2 = UNIT ? ddu : dd[NE - 2];
    Ap[NE - 2] = fmaf(dm2, p[NE - 2], c * p[NE - 4]) -
                 fmaf(c4, p[NE - 3], c3 * p[NE - 1]);
    float dm1 = (UNIT ? ddu : dd[NE - 1]) - c4;
    Ap[NE - 1] = fmaf(dm1, p[NE - 1], c * p[NE - 3]) - c3 * p[NE - 2];
  }
}

// ---- 4-wave dual-system CG (X and Y in one wave), 1 barrier/iteration ----
__device__ void cg_dual(float coef, float* ddX, float* rX, float* xX,
                        float* ddY, float* rY, float* xY, const float* hx,
                        int lane, int lw, int rr, float* P, float* E) {
  const float c = coef, c3 = 3.f * coef, c4 = 4.f * coef;
  const bool isF = (lw == 0), isL = (lw == 3);
#pragma unroll
  for (int e = 0; e < NE; ++e) {
    ddX[e] += 6.f * coef;
    ddY[e] += 6.f * coef;
  }
  float pX[NE], ApX[NE], pY[NE], ApY[NE];
  applyA8<false>(xX, ApX, ddX, 0.f, c, c3, c4, hx[0], hx[1], hx[4], hx[5], lane, isF, isL);
  applyA8<false>(xY, ApY, ddY, 0.f, c, c3, c4, hx[2], hx[3], hx[6], hx[7], lane, isF, isL);
  float sX = 0.f, sY = 0.f;
#pragma unroll
  for (int e = 0; e < NE; ++e) {
    rX[e] -= ApX[e]; pX[e] = rX[e]; sX = fmaf(rX[e], rX[e], sX);
    rY[e] -= ApY[e]; pY[e] = rY[e]; sY = fmaf(rY[e], rY[e], sY);
  }
  sX = dpp_sum_f32(sX);
  sY = dpp_sum_f32(sY);
  {
    float* pt = P + (rr * 4 + lw) * 8;
    float* ed = E + (rr * 4 + lw) * 8;
    if (lane == 0) {
      pt[0] = sX; pt[1] = sY;
      ed[0] = rX[0]; ed[1] = rX[1]; ed[2] = rY[0]; ed[3] = rY[1];
    }
    if (lane == 63) {
      ed[4] = rX[NE - 2]; ed[5] = rX[NE - 1]; ed[6] = rY[NE - 2]; ed[7] = rY[NE - 1];
    }
  }
  __syncthreads();
  float rsX = 0.f, rsY = 0.f;
#pragma unroll
  for (int w = 0; w < 4; ++w) {
    const float* q = P + (rr * 4 + w) * 8;
    rsX += q[0]; rsY += q[1];
  }
  float hrLX0 = 0, hrLX1 = 0, hpLX0 = 0, hpLX1 = 0;
  float hrLY0 = 0, hrLY1 = 0, hpLY0 = 0, hpLY1 = 0;
  float hrRX0 = 0, hrRX1 = 0, hpRX0 = 0, hpRX1 = 0;
  float hrRY0 = 0, hrRY1 = 0, hpRY0 = 0, hpRY1 = 0;
  if (!isF) {
    const float* ed = E + (rr * 4 + lw - 1) * 8;
    hrLX0 = ed[4]; hrLX1 = ed[5]; hrLY0 = ed[6]; hrLY1 = ed[7];
    hpLX0 = hrLX0; hpLX1 = hrLX1; hpLY0 = hrLY0; hpLY1 = hrLY1;
  }
  if (!isL) {
    const float* ed = E + (rr * 4 + lw + 1) * 8;
    hrRX0 = ed[0]; hrRX1 = ed[1]; hrRY0 = ed[2]; hrRY1 = ed[3];
    hpRX0 = hrRX0; hpRX1 = hrRX1; hpRY0 = hrRY0; hpRY1 = hrRY1;
  }
  bool dX = false, dY = false;
  for (int t = 0; t < 30; ++t) {
    int par = (t + 1) & 1;
    float* Pb = P + par * 128;
    float* Eb = E + par * 128;
    applyA8<false>(pX, ApX, ddX, 0.f, c, c3, c4, hpLX0, hpLX1, hpRX0, hpRX1, lane, isF, isL);
    applyA8<false>(pY, ApY, ddY, 0.f, c, c3, c4, hpLY0, hpLY1, hpRY0, hpRY1, lane, isF, isL);
    float paX = 0, aaX = 0, raX = 0, paY = 0, aaY = 0, raY = 0;
#pragma unroll
    for (int e = 0; e < NE; ++e) {
      paX = fmaf(pX[e], ApX[e], paX);
      aaX = fmaf(ApX[e], ApX[e], aaX);
      raX = fmaf(rX[e], ApX[e], raX);
      paY = fmaf(pY[e], ApY[e], paY);
      aaY = fmaf(ApY[e], ApY[e], aaY);
      raY = fmaf(rY[e], ApY[e], raY);
    }
    paX = dpp_sum_f32(paX); aaX = dpp_sum_f32(aaX); raX = dpp_sum_f32(raX);
    paY = dpp_sum_f32(paY); aaY = dpp_sum_f32(aaY); raY = dpp_sum_f32(raY);
    {
      float* pt = Pb + (rr * 4 + lw) * 8;
      float* ed = Eb + (rr * 4 + lw) * 8;
      if (lane == 0) {
        pt[0] = paX; pt[1] = aaX; pt[2] = raX; pt[3] = paY; pt[4] = aaY; pt[5] = raY;
        ed[0] = ApX[0]; ed[1] = ApX[1]; ed[2] = ApY[0]; ed[3] = ApY[1];
      }
      if (lane == 63) {
        ed[4] = ApX[NE - 2]; ed[5] = ApX[NE - 1]; ed[6] = ApY[NE - 2]; ed[7] = ApY[NE - 1];
      }
    }
    __syncthreads();
    float PpX = 0, AaX = 0, RaX = 0, PpY = 0, AaY = 0, RaY = 0;
#pragma unroll
    for (int w = 0; w < 4; ++w) {
      const float* q = Pb + (rr * 4 + w) * 8;
      PpX += q[0]; AaX += q[1]; RaX += q[2];
      PpY += q[3]; AaY += q[4]; RaY += q[5];
    }
    float aX = __fdividef(rsX, PpX + 1e-12f);
    float rsnX = fmaf(aX * aX, AaX, fmaf(-2.f * aX, RaX, rsX));
    float aY = __fdividef(rsY, PpY + 1e-12f);
    float rsnY = fmaf(aY * aY, AaY, fmaf(-2.f * aY, RaY, rsY));
    if (!dX) {
#pragma unroll
      for (int e = 0; e < NE; ++e) {
        xX[e] = fmaf(aX, pX[e], xX[e]);
        rX[e] = fmaf(-aX, ApX[e], rX[e]);
      }
    }
    if (!dY) {
#pragma unroll
      for (int e = 0; e < NE; ++e) {
        xY[e] = fmaf(aY, pY[e], xY[e]);
        rY[e] = fmaf(-aY, ApY[e], rY[e]);
      }
    }
    bool d1X = dX || (rsnX < 1e-12f);  // == sqrt < 1e-6 (monotone)
    bool d1Y = dY || (rsnY < 1e-12f);
    float btaX = __fdividef(rsnX, rsX + 1e-12f);
    float btaY = __fdividef(rsnY, rsY + 1e-12f);
    if (!d1X) {
#pragma unroll
      for (int e = 0; e < NE; ++e) pX[e] = fmaf(btaX, pX[e], rX[e]);
      rsX = rsnX;
      if (!isF) {
        const float* eL = Eb + (rr * 4 + lw - 1) * 8;
        hrLX0 = fmaf(-aX, eL[4], hrLX0); hpLX0 = fmaf(btaX, hpLX0, hrLX0);
        hrLX1 = fmaf(-aX, eL[5], hrLX1); hpLX1 = fmaf(btaX, hpLX1, hrLX1);
      }
      if (!isL) {
        const float* eR = Eb + (rr * 4 + lw + 1) * 8;
        hrRX0 = fmaf(-aX, eR[0], hrRX0); hpRX0 = fmaf(btaX, hpRX0, hrRX0);
        hrRX1 = fmaf(-aX, eR[1], hrRX1); hpRX1 = fmaf(btaX, hpRX1, hrRX1);
      }
    }
    if (!d1Y) {
#pragma unroll
      for (int e = 0; e < NE; ++e) pY[e] = fmaf(btaY, pY[e], rY[e]);
      rsY = rsnY;
      if (!isF) {
        const float* eL = Eb + (rr * 4 + lw - 1) * 8;
        hrLY0 = fmaf(-aY, eL[6], hrLY0); hpLY0 = fmaf(btaY, hpLY0, hrLY0);
        hrLY1 = fmaf(-aY, eL[7], hrLY1); hpLY1 = fmaf(btaY, hpLY1, hrLY1);
      }
      if (!isL) {
        const float* eR = Eb + (rr * 4 + lw + 1) * 8;
        hrRY0 = fmaf(-aY, eR[2], hrRY0); hpRY0 = fmaf(btaY, hpRY0, hrRY0);
        hrRY1 = fmaf(-aY, eR[3], hrRY1); hpRY1 = fmaf(btaY, hpRY1, hrRY1);
      }
    }
    dX = d1X;
    dY = d1Y;
  }
}

// ---- 4-wave single-system CG (unit diag), same scheme ----
__device__ void cg_single(float coef, float* r, float* x, int lane, int lw,
                          int rr, float* P, float* E) {
  const float c = coef, c3 = 3.f * coef, c4 = 4.f * coef;
  const float ddu = 6.f * coef + (1.0f + 1e-6f);
  const bool isF = (lw == 0), isL = (lw == 3);
  float p[NE], Ap[NE];
  applyA8<true>(x, Ap, nullptr, ddu, c, c3, c4, 0.f, 0.f, 0.f, 0.f, lane, isF, isL);
  float s0 = 0.f;
#pragma unroll
  for (int e = 0; e < NE; ++e) {
    r[e] -= Ap[e];
    p[e] = r[e];
    s0 = fmaf(r[e], r[e], s0);
  }
  s0 = dpp_sum_f32(s0);
  {
    float* pt = P + (rr * 4 + lw) * 8;
    float* ed = E + (rr * 4 + lw) * 8;
    if (lane == 0) { pt[0] = s0; ed[0] = r[0]; ed[1] = r[1]; }
    if (lane == 63) { ed[4] = r[NE - 2]; ed[5] = r[NE - 1]; }
  }
  __syncthreads();
  float rs = 0.f;
#pragma unroll
  for (int w = 0; w < 4; ++w) rs += (P + (rr * 4 + w) * 8)[0];
  float hrL0 = 0, hrL1 = 0, hpL0 = 0, hpL1 = 0;
  float hrR0 = 0, hrR1 = 0, hpR0 = 0, hpR1 = 0;
  if (!isF) {
    const float* ed = E + (rr * 4 + lw - 1) * 8;
    hrL0 = ed[4]; hrL1 = ed[5]; hpL0 = hrL0; hpL1 = hrL1;
  }
  if (!isL) {
    const float* ed = E + (rr * 4 + lw + 1) * 8;
    hrR0 = ed[0]; hrR1 = ed[1]; hpR0 = hrR0; hpR1 = hrR1;
  }
  bool done = false;
  for (int t = 0; t < 30; ++t) {
    int par = (t + 1) & 1;
    float* Pb = P + par * 128;
    float* Eb = E + par * 128;
    applyA8<true>(p, Ap, nullptr, ddu, c, c3, c4, hpL0, hpL1, hpR0, hpR1, lane, isF, isL);
    float pa = 0, aa = 0, ra = 0;
#pragma unroll
    for (int e = 0; e < NE; ++e) {
      pa = fmaf(p[e], Ap[e], pa);
      aa = fmaf(Ap[e], Ap[e], aa);
      ra = fmaf(r[e], Ap[e], ra);
    }
    pa = dpp_sum_f32(pa);
    aa = dpp_sum_f32(aa);
    ra = dpp_sum_f32(ra);
    {
      float* pt = Pb + (rr * 4 + lw) * 8;
      float* ed = Eb + (rr * 4 + lw) * 8;
      if (lane == 0) { pt[0] = pa; pt[1] = aa; pt[2] = ra; ed[0] = Ap[0]; ed[1] = Ap[1]; }
      if (lane == 63) { ed[4] = Ap[NE - 2]; ed[5] = Ap[NE - 1]; }
    }
    __syncthreads();
    float Pp = 0, Aa = 0, Ra = 0;
#pragma unroll
    for (int w = 0; w < 4; ++w) {
      const float* q = Pb + (rr * 4 + w) * 8;
      Pp += q[0]; Aa += q[1]; Ra += q[2];
    }
    float a = __fdividef(rs, Pp + 1e-12f);
    float rsn = fmaf(a * a, Aa, fmaf(-2.f * a, Ra, rs));
    if (!done) {
#pragma unroll
      for (int e = 0; e < NE; ++e) {
        x[e] = fmaf(a, p[e], x[e]);
        r[e] = fmaf(-a, Ap[e], r[e]);
      }
    }
    bool d1 = done || (rsn < 1e-12f);
    float bta = __fdividef(rsn, rs + 1e-12f);
    if (!d1) {
#pragma unroll
      for (int e = 0; e < NE; ++e) p[e] = fmaf(bta, p[e], r[e]);
      rs = rsn;
      if (!isF) {
        const float* eL = Eb + (rr * 4 + lw - 1) * 8;
        hrL0 = fmaf(-a, eL[4], hrL0); hpL0 = fmaf(bta, hpL0, hrL0);
        hrL1 = fmaf(-a, eL[5], hrL1); hpL1 = fmaf(bta, hpL1, hrL1);
      }
      if (!isL) {
        const float* eR = Eb + (rr * 4 + lw + 1) * 8;
        hrR0 = fmaf(-a, eR[0], hrR0); hpR0 = fmaf(bta, hpR0, hrR0);
        hrR1 = fmaf(-a, eR[1], hrR1); hpR1 = fmaf(bta, hpR1, hrR1);
      }
    }
    done = d1;
  }
}

// ---- mega kernel: 1 block per batch b; 16 waves = 4 rows x 4 segments ----
__global__ __launch_bounds__(1024) void mega_kernel(
    const float* __restrict__ s, const float* __restrict__ eIF,
    const float* __restrict__ xm, const float* __restrict__ ym,
    const float* __restrict__ sum_x, const float* __restrict__ sum_y,
    const float* __restrict__ lamuda, const float* __restrict__ init_freqs,
    const int* __restrict__ mode_mask, const float* __restrict__ alpha_p,
    const float* __restrict__ beta_p, const float* __restrict__ var_p,
    const float* __restrict__ fs_p, const int* __restrict__ iter_p,
    const float* __restrict__ fe_w1, const float* __restrict__ fe_b1,
    const float* __restrict__ fe_w2, const float* __restrict__ fe_b2,
    const float* __restrict__ pr_w1, const float* __restrict__ pr_b1,
    const float* __restrict__ pr_w2, const float* __restrict__ pr_b2,
    const float* __restrict__ pr_w3, const float* __restrict__ pr_b3,
    const float* __restrict__ iter_w_p, float* __restrict__ out_eIF,
    float* __restrict__ out_xm, float* __restrict__ out_ym,
    float* __restrict__ out_bsx, float* __restrict__ out_bsy,
    float* __restrict__ out_lam, float* __restrict__ out_scal) {
  __shared__ double sh_avg[Bq];
  __shared__ double sh_h1[Bq][32];
  __shared__ double sh_zz[Bq][18];
  __shared__ double sh_z1[Bq][64];
  __shared__ double sh_z2[Bq][32];
  __shared__ double sh_res[Bq][2];
  __shared__ double sh_hdr[4];
  __shared__ double sh_un[4];
  __shared__ double sh_segT[4][4], sh_y0v[4];
  __shared__ double sh_segT2[4][4], sh_y02v[4];
  __shared__ float sh_part[2 * 128];  // [parity][row][wave][8]
  __shared__ float sh_edge[2 * 128];
  __shared__ float sh_exy[4 * 4 * 4];
  __shared__ float sh_bsx[Nq], sh_bsy[Nq];

  const int tid = threadIdx.x;
  const int wv = tid >> 6, lane = tid & 63;
  const int rr = wv >> 2, lw = wv & 3;
  const int b = blockIdx.x;
  const int row = b * Kq + rr;
  const int bb = b * Nq, base = row * Nq;
  const int seg0 = lw * SEG;
  const bool isF = (lw == 0), isL = (lw == 3);

  for (int j = tid; j < Nq; j += 1024) {
    sh_bsx[j] = 0.f;
    sh_bsy[j] = 0.f;
  }

  // ---- hyperparameter MLP (once per block, f64 deterministic) ----
  double alpha = (double)alpha_p[0], beta = (double)beta_p[0];
  double iterv = (double)iter_p[0];
  if (tid < Bq) {
    double avg = 0.0;
#pragma unroll
    for (int k = 0; k < Kq; ++k) avg += (double)init_freqs[tid * Kq + k];
    sh_avg[tid] = avg * (1.0 / Kq);
  }
  __syncthreads();
  if (tid < 256) {
    int b2 = tid >> 5, j = tid & 31;
    double v = (double)fe_w1[j] * sh_avg[b2] + (double)fe_b1[j];
    sh_h1[b2][j] = v > 0.0 ? v : 0.0;
  }
  __syncthreads();
  if (tid < 128) {
    int b2 = tid >> 4, j = tid & 15;
    double acc = (double)fe_b2[j];
    for (int i = 0; i < 32; ++i) acc += (double)fe_w2[j * 32 + i] * sh_h1[b2][i];
    sh_zz[b2][j] = acc > 0.0 ? acc : 0.0;
  }
  if (tid >= 128 && tid < 128 + Bq) {
    sh_zz[tid - 128][16] = alpha;
    sh_zz[tid - 128][17] = beta;
  }
  __syncthreads();
  if (tid < 512) {
    int b2 = tid >> 6, j = tid & 63;
    double acc = (double)pr_b1[j];
    for (int i = 0; i < 18; ++i) acc += (double)pr_w1[j * 18 + i] * sh_zz[b2][i];
    sh_z1[b2][j] = acc > 0.0 ? acc : 0.0;
  }
  __syncthreads();
  if (tid < 256) {
    int b2 = tid >> 5, j = tid & 31;
    double acc = (double)pr_b2[j];
    for (int i = 0; i < 64; ++i) acc += (double)pr_w2[j * 64 + i] * sh_z1[b2][i];
    sh_z2[b2][j] = acc > 0.0 ? acc : 0.0;
  }
  __syncthreads();
  if (tid < 16) {
    int b2 = tid >> 1, c = tid & 1;
    double acc = (double)pr_b3[c];
    for (int i = 0; i < 32; ++i) acc += (double)pr_w3[c * 32 + i] * sh_z2[b2][i];
    double fac = 1.0 / (1.0 + exp(-(double)iter_w_p[0] * iterv));
    sh_res[b2][c] = tanh(acc) * fac * 0.1;
  }
  __syncthreads();
  if (tid == 0) {
    double r0 = 0.0, r1 = 0.0;
    for (int q = 0; q < Bq; ++q) {
      r0 += sh_res[q][0];
      r1 += sh_res[q][1];
    }
    double na = fmin(fmax(alpha + r0 * alpha * (1.0 / Bq), 1e-6), 0.01);
    double nb2 = fmin(fmax(beta + r1 * beta * (1.0 / Bq), 1e-6), 0.1);
    double betathr = fmin(pow(10.0, iterv / 36.0 - 10.0), nb2);
    sh_hdr[0] = na;
    sh_hdr[1] = 2.0 / na;       // coefA
    sh_hdr[2] = 2.0 / betathr;  // coefS
    sh_hdr[3] = 1.0 / na;       // inv_alpha
    if (blockIdx.x == 0) {
      out_scal[0] = (float)na;
      out_scal[1] = (float)nb2;
    }
  }
  __syncthreads();
  const float coefA = (float)sh_hdr[1];
  const float coefS = (float)sh_hdr[2];
  const double inva = sh_hdr[3];

  // ---- tv (own segment, f64) + u-norm partials (row 0 publishes) ----
  double tv[NE];
  {
    double n0 = 0.0;
#pragma unroll
    for (int e = 0; e < NE; ++e) {
      int gi = bb + seg0 + lane * NE + e;
      tv[e] = (double)s[gi] - (double)sum_x[gi] - (double)sum_y[gi] -
              (double)lamuda[gi] * inva;
      n0 += tv[e] * tv[e];
    }
    double np = wave_sum_d(n0);
    if (rr == 0 && lane == 0) sh_un[lw] = np;
  }
  // ---- eIF segment scan (per row) ----
  const double dx = 1.0 / (double)fs_p[0];
  const double c0 = PI_D * dx;
  double ev[NE], pl[NE];
#pragma unroll
  for (int e = 0; e < NE; ++e) ev[e] = (double)eIF[base + seg0 + lane * NE + e];
  pl[0] = ev[0];
#pragma unroll
  for (int e = 1; e < NE; ++e) pl[e] = pl[e - 1] + ev[e];
  double offs_w = lane_excl_prefix_d(pl[NE - 1], lane);
  {
    double segT = __shfl(offs_w + pl[NE - 1], 63, 64);
    if (lane == 0) sh_segT[rr][lw] = segT;
    if (isF && lane == 0) sh_y0v[rr] = ev[0];
  }
  __syncthreads();
  double offs = offs_w;
  for (int w = 0; w < 3; ++w)
    if (lw > w) offs += sh_segT[rr][w];
  double y0 = sh_y0v[rr];
  {
    double nsq = sh_un[0] + sh_un[1] + sh_un[2] + sh_un[3];
    double nn = sqrt(nsq);
    double ee = sqrt((double)Nq * (double)var_p[0]);
    double scale = (nn > ee) ? ee / fmax(nn, 1e-30) : 1.0;
    double oms = 1.0 - scale;
#pragma unroll
    for (int e = 0; e < NE; ++e) tv[e] *= oms;
  }

  // ---- trig + build both systems ----
  float ddX[NE], rX[NE], xX[NE], ddY[NE], rY[NE], xY[NE];
#pragma unroll
  for (int e = 0; e < NE; ++e) {
    int i = seg0 + lane * NE + e;
    double ph = c0 * (2.0 * (offs + pl[e]) - ev[e] - y0);  // 2*pi*cumtrapz
    float sn, cs;
    fast_sincos_ph(ph, &sn, &cs);
    float xmv = xm[base + i], ymv = ym[base + i];
    double resid = tv[e] + (double)xmv * (double)cs + (double)ymv * (double)sn;
    ddX[e] = cs * cs + 1e-6f;
    rX[e] = (float)((double)cs * resid);
    xX[e] = xmv;
    ddY[e] = sn * sn + 1e-6f;
    rY[e] = (float)((double)sn * resid);
    xY[e] = ymv;
  }
  float hx[8] = {0, 0, 0, 0, 0, 0, 0, 0};
  if (!isF) {
    hx[0] = xm[base + seg0 - 2];
    hx[1] = xm[base + seg0 - 1];
    hx[2] = ym[base + seg0 - 2];
    hx[3] = ym[base + seg0 - 1];
  }
  if (!isL) {
    hx[4] = xm[base + seg0 + SEG];
    hx[5] = xm[base + seg0 + SEG + 1];
    hx[6] = ym[base + seg0 + SEG];
    hx[7] = ym[base + seg0 + SEG + 1];
  }

  // ---- dual CG: xs in xX, ys in xY ----
  cg_dual(coefA, ddX, rX, xX, ddY, rY, xY, hx, lane, lw, rr, sh_part, sh_edge);

  // ---- deltaIF (xs/ys in registers; tiny cross-wave edge exchange) ----
  {
    float* ex = sh_exy + (rr * 4 + lw) * 4;
    if (lane == 0) { ex[0] = xX[0]; ex[1] = xY[0]; }
    if (lane == 63) { ex[2] = xX[NE - 1]; ex[3] = xY[NE - 1]; }
  }
  __syncthreads();
  {
    float invdx = (float)fs_p[0], inv2dx = 0.5f * invdx;
    float xl = dpp_up1(xX[NE - 1]), xr = dpp_dn1(xX[0]);
    float yl = dpp_up1(xY[NE - 1]), yr = dpp_dn1(xY[0]);
    if (!isF && lane == 0) {
      const float* ex = sh_exy + (rr * 4 + lw - 1) * 4;
      xl = ex[2];
      yl = ex[3];
    }
    if (!isL && lane == 63) {
      const float* ex = sh_exy + (rr * 4 + lw + 1) * 4;
      xr = ex[0];
      yr = ex[1];
    }
#pragma unroll
    for (int e = 0; e < NE; ++e) {
      int i = seg0 + lane * NE + e;
      float xm1 = (e >= 1) ? xX[e - 1] : xl;
      float xp1 = (e <= NE - 2) ? xX[e + 1] : xr;
      float ym1 = (e >= 1) ? xY[e - 1] : yl;
      float yp1 = (e <= NE - 2) ? xY[e + 1] : yr;
      float xb, yb;
      if (i == 0) {
        xb = (xp1 - xX[e]) * invdx;
        yb = (yp1 - xY[e]) * invdx;
      } else if (i == Nq - 1) {
        xb = (xX[e] - xm1) * invdx;
        yb = (xY[e] - ym1) * invdx;
      } else {
        xb = (xp1 - xm1) * inv2dx;
        yb = (yp1 - ym1) * inv2dx;
      }
      float denom = xX[e] * xX[e] + xY[e] * xY[e] + 1e-12f;
      rX[e] = (xX[e] * yb - xY[e] * xb) / (denom * (float)TWO_PI_D);
      ddX[e] = 0.0f;  // smooth solution storage, x0 = 0
    }
  }

  // ---- smooth CG (single system per row, 4 waves) ----
  cg_single(coefS, rX, ddX, lane, lw, rr, sh_part, sh_edge);

  // ---- epilogue: outputs + new-phase contributions ----
  bool active = mode_mask[row] != 0;
  double eifn[NE];
#pragma unroll
  for (int e = 0; e < NE; ++e) {
    int i = seg0 + lane * NE + e;
    double eifv = (double)eIF[base + i];
    eifn[e] = active ? (eifv - 0.5 * (double)ddX[e]) : eifv;
    out_eIF[base + i] = (float)eifn[e];
    out_xm[base + i] = active ? xX[e] : xm[base + i];
    out_ym[base + i] = active ? xY[e] : ym[base + i];
  }
  pl[0] = eifn[0];
#pragma unroll
  for (int e = 1; e < NE; ++e) pl[e] = pl[e - 1] + eifn[e];
  offs_w = lane_excl_prefix_d(pl[NE - 1], lane);
  {
    double segT = __shfl(offs_w + pl[NE - 1], 63, 64);
    if (lane == 0) sh_segT2[rr][lw] = segT;
    if (isF && lane == 0) sh_y02v[rr] = eifn[0];
  }
  __syncthreads();
  {
    double offs2 = offs_w;
    for (int w = 0; w < 3; ++w)
      if (lw > w) offs2 += sh_segT2[rr][w];
    double y02 = sh_y02v[rr];
#pragma unroll
    for (int e = 0; e < NE; ++e) {
      int i = seg0 + lane * NE + e;
      double ph = c0 * (2.0 * (offs2 + pl[e]) - eifn[e] - y02);
      float sn, cs;
      fast_sincos_ph(ph, &sn, &cs);
      if (active) {
        atomicAdd(&sh_bsx[i], xX[e] * cs);
        atomicAdd(&sh_bsy[i], xY[e] * sn);
      }
    }
  }
  __syncthreads();

  // ---- final: bsx/bsy + u + new lamuda (folded final_kernel) ----
  {
    double na = sh_hdr[0];
    double nsq = sh_un[0] + sh_un[1] + sh_un[2] + sh_un[3];
    double nn = sqrt(nsq);
    double ee = sqrt((double)Nq * (double)var_p[0]);
    double scale = (nn > ee) ? ee / fmax(nn, 1e-30) : 1.0;
#pragma unroll
    for (int j = 0; j < 2; ++j) {
      int i = tid + j * 1024;
      int gi = bb + i;
      double t = (double)s[gi] - (double)sum_x[gi] - (double)sum_y[gi] -
                 (double)lamuda[gi] * inva;
      double u = t * scale;
      double bx = (double)sh_bsx[i], by = (double)sh_bsy[i];
      double nl = (double)lamuda[gi] + na * (u + bx + by - (double)s[gi]);
      out_bsx[gi] = (float)bx;
      out_bsy[gi] = (float)by;
      out_lam[gi] = (float)nl;
    }
  }
}

// ---------------- launcher ----------------
extern "C" void kernel_launch(void* const* d_in, const int* in_sizes, int n_in,
                              void* d_out, int out_size, void* d_ws, size_t ws_size,
                              hipStream_t stream) {
  (void)in_sizes; (void)n_in; (void)out_size; (void)d_ws; (void)ws_size;
  const float* s = (const float*)d_in[0];
  const float* eIF = (const float*)d_in[1];
  const float* xm = (const float*)d_in[2];
  const float* ym = (const float*)d_in[3];
  const float* sum_x = (const float*)d_in[4];
  const float* sum_y = (const float*)d_in[5];
  const float* lamuda = (const float*)d_in[6];
  const float* init_freqs = (const float*)d_in[7];
  const int* mode_mask = (const int*)d_in[8];
  const float* alpha = (const float*)d_in[9];
  const float* beta = (const float*)d_in[10];
  const float* var = (const float*)d_in[11];
  const float* fs = (const float*)d_in[12];
  const int* iteration = (const int*)d_in[13];
  const float* fe_w1 = (const float*)d_in[14];
  const float* fe_b1 = (const float*)d_in[15];
  const float* fe_w2 = (const float*)d_in[16];
  const float* fe_b2 = (const float*)d_in[17];
  const float* pr_w1 = (const float*)d_in[18];
  const float* pr_b1 = (const float*)d_in[19];
  const float* pr_w2 = (const float*)d_in[20];
  const float* pr_b2 = (const float*)d_in[21];
  const float* pr_w3 = (const float*)d_in[22];
  const float* pr_b3 = (const float*)d_in[23];
  const float* iter_weight = (const float*)d_in[24];

  float* out = (float*)d_out;
  const int BN = Bq * Nq;  // 16384
  const int BKN = 4 * BN;  // 65536
  float* out_eIF = out;
  float* out_xm = out + BKN;
  float* out_ym = out + 2 * BKN;
  float* out_bsx = out + 3 * BKN;
  float* out_bsy = out + 3 * BKN + BN;
  float* out_lam = out + 3 * BKN + 2 * BN;
  float* out_scal = out + 3 * BKN + 3 * BN;  // [new_alpha, new_beta]

  mega_kernel<<<Bq, 1024, 0, stream>>>(
      s, eIF, xm, ym, sum_x, sum_y, lamuda, init_freqs, mode_mask, alpha, beta,
      var, fs, iteration, fe_w1, fe_b1, fe_w2, fe_b2, pr_w1, pr_b1, pr_w2,
      pr_b2, pr_w3, pr_b3, iter_weight, out_eIF, out_xm, out_ym, out_bsx,
      out_bsy, out_lam, out_scal);
}

// Round 9
// 232.764 us; speedup vs baseline: 1.3952x; 1.3952x over previous
//
#include <hip/hip_runtime.h>
#include <math.h>

#define Nq 2048
#define Bq 8
#define Kq 4
#define NL 32  // elements per lane (2048 / 64)
#define TWO_PI_D 6.283185307179586
#define PI_D 3.141592653589793
#define INV2PI_D 0.15915494309189535

// ---------------- wave helpers ----------------

__device__ __forceinline__ double wave_sum_d(double v) {
#pragma unroll
  for (int off = 1; off < 64; off <<= 1) v += __shfl_xor(v, off, 64);
  return v;
}

// Canonical GCN DPP wave64 sum; uniform result via readlane 63.
__device__ __forceinline__ float dpp_sum_f32(float v) {
  v += __int_as_float(__builtin_amdgcn_update_dpp(0, __float_as_int(v), 0x111, 0xf, 0xf, false));  // row_shr:1
  v += __int_as_float(__builtin_amdgcn_update_dpp(0, __float_as_int(v), 0x112, 0xf, 0xf, false));  // row_shr:2
  v += __int_as_float(__builtin_amdgcn_update_dpp(0, __float_as_int(v), 0x114, 0xf, 0xe, false));  // row_shr:4
  v += __int_as_float(__builtin_amdgcn_update_dpp(0, __float_as_int(v), 0x118, 0xf, 0xc, false));  // row_shr:8
  v += __int_as_float(__builtin_amdgcn_update_dpp(0, __float_as_int(v), 0x142, 0xa, 0xf, false));  // row_bcast:15
  v += __int_as_float(__builtin_amdgcn_update_dpp(0, __float_as_int(v), 0x143, 0xc, 0xf, false));  // row_bcast:31
  return __int_as_float(__builtin_amdgcn_readlane(__float_as_int(v), 63));
}

__device__ __forceinline__ float dpp_up1(float v) {  // lane i <- lane i-1
  return __int_as_float(__builtin_amdgcn_update_dpp(0, __float_as_int(v), 0x138, 0xf, 0xf, false));  // wave_shr:1
}
__device__ __forceinline__ float dpp_dn1(float v) {  // lane i <- lane i+1
  return __int_as_float(__builtin_amdgcn_update_dpp(0, __float_as_int(v), 0x130, 0xf, 0xf, false));  // wave_shl:1
}

__device__ __forceinline__ double lane_excl_prefix_d(double T, int lane) {
  double acc = T;
#pragma unroll
  for (int off = 1; off < 64; off <<= 1) {
    double t = __shfl_up(acc, off, 64);
    if (lane >= off) acc += t;
  }
  return acc - T;
}

__device__ __forceinline__ void fast_sincos_ph(double ph, float* sn, float* cs) {
  double k = trunc(ph * INV2PI_D);
  float phr = (float)(ph - k * TWO_PI_D);
  __sincosf(phr, sn, cs);
}

// Full matvec Ap = (coef*opedoub + diag(de)) p, with dd[e] = 6*coef + de[e]
// folded in. Endpoint rows (global 0,1,N-2,N-1) fixed up on lanes 0/63.
template <bool UNIT>
__device__ __forceinline__ void applyA(const float* p, float* Ap,
                                       const float* dd, float c, float c3,
                                       float c4, float ddu, int lane) {
  float lm1 = dpp_up1(p[NL - 1]);
  float lm2 = dpp_up1(p[NL - 2]);
  float rp1 = dpp_dn1(p[0]);
  float rp2 = dpp_dn1(p[1]);
#pragma unroll
  for (int e = 0; e < NL; ++e) {
    float m2 = (e >= 2) ? p[e - 2] : (e == 1 ? lm1 : lm2);
    float m1 = (e >= 1) ? p[e - 1] : lm1;
    float q1 = (e <= NL - 2) ? p[e + 1] : rp1;
    float q2 = (e <= NL - 3) ? p[e + 2] : (e == NL - 2 ? rp1 : rp2);
    float t1 = m2 + q2, t2 = m1 + q1;
    float u = fmaf(c, t1, -(c4 * t2));
    float d = UNIT ? ddu : dd[e];
    Ap[e] = fmaf(d, p[e], u);
  }
  if (lane == 0) {
    float d0 = (UNIT ? ddu : dd[0]) - c4;  // = 2c + de0
    Ap[0] = fmaf(d0, p[0], fmaf(c, p[2], -(c3 * p[1])));
    float d1 = UNIT ? ddu : dd[1];
    Ap[1] = fmaf(d1, p[1], -(c3 * p[0])) + fmaf(c, p[3], -(c4 * p[2]));
  }
  if (lane == 63) {
    float dm2 = UNIT ? ddu : dd[NL - 2];
    Ap[NL - 2] = fmaf(dm2, p[NL - 2], c * p[NL - 4]) -
                 fmaf(c4, p[NL - 3], c3 * p[NL - 1]);
    float dm1 = (UNIT ? ddu : dd[NL - 1]) - c4;  // = 2c + de
    Ap[NL - 1] = fmaf(dm1, p[NL - 1], c * p[NL - 3]) - c3 * p[NL - 2];
  }
}

// Wave CG (f32 state, zero barriers) on (coef*opedoub + diag(de)) z = rhs.
// de passed in dd[] (or unit diag); dd is destructively updated to 6c+de.
// In: x = x0, r = rhs. Out: x = solution. Reference freeze semantics.
template <bool UNIT>
__device__ __forceinline__ void cg_wave_f(float coef, float* dd, float* r,
                                          float* x, int lane) {
  const float c = coef, c3 = 3.0f * coef, c4 = 4.0f * coef;
  const float ddu = 6.0f * coef + (1.0f + 1e-6f);
  if (!UNIT) {
#pragma unroll
    for (int e = 0; e < NL; ++e) dd[e] += 6.0f * coef;
  }
  float p[NL], Ap[NL];
  applyA<UNIT>(x, Ap, dd, c, c3, c4, ddu, lane);
  float s0 = 0, s1 = 0, s2 = 0, s3 = 0;
#pragma unroll
  for (int e = 0; e < NL; ++e) {
    r[e] -= Ap[e];
    p[e] = r[e];
    float* acc = (e & 2) ? ((e & 1) ? &s3 : &s2) : ((e & 1) ? &s1 : &s0);
    *acc = fmaf(r[e], r[e], *acc);
  }
  float rsold = dpp_sum_f32((s0 + s1) + (s2 + s3));
  for (int it = 0; it < 30; ++it) {
    applyA<UNIT>(p, Ap, dd, c, c3, c4, ddu, lane);
    float d0 = 0, d1 = 0, d2 = 0, d3 = 0;
#pragma unroll
    for (int e = 0; e < NL; ++e) {
      float* acc = (e & 2) ? ((e & 1) ? &d3 : &d2) : ((e & 1) ? &d1 : &d0);
      *acc = fmaf(p[e], Ap[e], *acc);
    }
    float pap = dpp_sum_f32((d0 + d1) + (d2 + d3));
    float a = __fdividef(rsold, pap + 1e-12f);
    float t0 = 0, t1 = 0, t2 = 0, t3 = 0;
#pragma unroll
    for (int e = 0; e < NL; ++e) {
      x[e] = fmaf(a, p[e], x[e]);
      r[e] = fmaf(-a, Ap[e], r[e]);
      float* acc = (e & 2) ? ((e & 1) ? &t3 : &t2) : ((e & 1) ? &t1 : &t0);
      *acc = fmaf(r[e], r[e], *acc);
    }
    float rsnew = dpp_sum_f32((t0 + t1) + (t2 + t3));
    if (rsnew < 1e-12f) break;  // == sqrt(rsnew) < 1e-6 (monotone)
    float bta = __fdividef(rsnew, rsold + 1e-12f);
#pragma unroll
    for (int e = 0; e < NL; ++e) p[e] = fmaf(bta, p[e], r[e]);
    rsold = rsnew;
  }
}

// ---- mega kernel: 1 block per batch b; 8 waves = 4 rows x {X,Y} ----
// wave w: rr = w>>1 (row-in-batch), syst = w&1 (0=X, 1=Y). Each wave runs a
// full-row zero-barrier CG; 2 waves/SIMD co-resident for latency hiding.
__global__ __launch_bounds__(512, 2) void mega_kernel(
    const float* __restrict__ s, const float* __restrict__ eIF,
    const float* __restrict__ xm, const float* __restrict__ ym,
    const float* __restrict__ sum_x, const float* __restrict__ sum_y,
    const float* __restrict__ lamuda, const float* __restrict__ init_freqs,
    const int* __restrict__ mode_mask, const float* __restrict__ alpha_p,
    const float* __restrict__ beta_p, const float* __restrict__ var_p,
    const float* __restrict__ fs_p, const int* __restrict__ iter_p,
    const float* __restrict__ fe_w1, const float* __restrict__ fe_b1,
    const float* __restrict__ fe_w2, const float* __restrict__ fe_b2,
    const float* __restrict__ pr_w1, const float* __restrict__ pr_b1,
    const float* __restrict__ pr_w2, const float* __restrict__ pr_b2,
    const float* __restrict__ pr_w3, const float* __restrict__ pr_b3,
    const float* __restrict__ iter_w_p, float* __restrict__ out_eIF,
    float* __restrict__ out_xm, float* __restrict__ out_ym,
    float* __restrict__ out_bsx, float* __restrict__ out_bsy,
    float* __restrict__ out_lam, float* __restrict__ out_scal) {
  __shared__ double sh_avg[Bq];
  __shared__ double sh_h1[Bq][32];
  __shared__ double sh_zz[Bq][18];
  __shared__ double sh_z1[Bq][64];
  __shared__ double sh_z2[Bq][32];
  __shared__ double sh_res[Bq][2];
  __shared__ double sh_hdr[4];
  __shared__ double sh_scale_d;
  __shared__ float sh_xs[Kq][Nq], sh_ys[Kq][Nq];
  __shared__ float sh_bsx[Nq], sh_bsy[Nq];

  const int tid = threadIdx.x;
  const int wv = tid >> 6, lane = tid & 63;
  const int rr = wv >> 1, syst = wv & 1;
  const int b = blockIdx.x;
  const int row = b * Kq + rr;
  const int bb = b * Nq, base = row * Nq;

  for (int j = tid; j < Nq; j += 512) {
    sh_bsx[j] = 0.f;
    sh_bsy[j] = 0.f;
  }

  // ---- hyperparameter MLP (once per block, f64 deterministic) ----
  double alpha = (double)alpha_p[0], beta = (double)beta_p[0];
  double iterv = (double)iter_p[0];
  if (tid < Bq) {
    double avg = 0.0;
#pragma unroll
    for (int k = 0; k < Kq; ++k) avg += (double)init_freqs[tid * Kq + k];
    sh_avg[tid] = avg * (1.0 / Kq);
  }
  __syncthreads();
  if (tid < 256) {
    int b2 = tid >> 5, j = tid & 31;
    double v = (double)fe_w1[j] * sh_avg[b2] + (double)fe_b1[j];
    sh_h1[b2][j] = v > 0.0 ? v : 0.0;
  }
  __syncthreads();
  if (tid < 128) {
    int b2 = tid >> 4, j = tid & 15;
    double acc = (double)fe_b2[j];
    for (int i = 0; i < 32; ++i) acc += (double)fe_w2[j * 32 + i] * sh_h1[b2][i];
    sh_zz[b2][j] = acc > 0.0 ? acc : 0.0;
  }
  if (tid >= 128 && tid < 128 + Bq) {
    sh_zz[tid - 128][16] = alpha;
    sh_zz[tid - 128][17] = beta;
  }
  __syncthreads();
  {
    int b2 = tid >> 6, j = tid & 63;
    double acc = (double)pr_b1[j];
    for (int i = 0; i < 18; ++i) acc += (double)pr_w1[j * 18 + i] * sh_zz[b2][i];
    sh_z1[b2][j] = acc > 0.0 ? acc : 0.0;
  }
  __syncthreads();
  if (tid < 256) {
    int b2 = tid >> 5, j = tid & 31;
    double acc = (double)pr_b2[j];
    for (int i = 0; i < 64; ++i) acc += (double)pr_w2[j * 64 + i] * sh_z1[b2][i];
    sh_z2[b2][j] = acc > 0.0 ? acc : 0.0;
  }
  __syncthreads();
  if (tid < 16) {
    int b2 = tid >> 1, c = tid & 1;
    double acc = (double)pr_b3[c];
    for (int i = 0; i < 32; ++i) acc += (double)pr_w3[c * 32 + i] * sh_z2[b2][i];
    double fac = 1.0 / (1.0 + exp(-(double)iter_w_p[0] * iterv));
    sh_res[b2][c] = tanh(acc) * fac * 0.1;
  }
  __syncthreads();
  if (tid == 0) {
    double r0 = 0.0, r1 = 0.0;
    for (int q = 0; q < Bq; ++q) { r0 += sh_res[q][0]; r1 += sh_res[q][1]; }
    double na = fmin(fmax(alpha + r0 * alpha * (1.0 / Bq), 1e-6), 0.01);
    double nb2 = fmin(fmax(beta + r1 * beta * (1.0 / Bq), 1e-6), 0.1);
    double betathr = fmin(pow(10.0, iterv / 36.0 - 10.0), nb2);
    sh_hdr[0] = na;
    sh_hdr[1] = 2.0 / na;       // coefA
    sh_hdr[2] = 2.0 / betathr;  // coefS
    sh_hdr[3] = 1.0 / na;       // inv_alpha
    if (b == 0) {
      out_scal[0] = (float)na;
      out_scal[1] = (float)nb2;
    }
  }
  __syncthreads();
  const float coefA = (float)sh_hdr[1];
  const float coefS = (float)sh_hdr[2];
  const double inva = sh_hdr[3];

  // ---- u scale for batch b (per-wave redundant, f64) ----
  double tv[NL];
  {
    double n0 = 0.0, n1 = 0.0;
#pragma unroll
    for (int e = 0; e < NL; ++e) {
      int gi = bb + lane * NL + e;
      tv[e] = (double)s[gi] - (double)sum_x[gi] - (double)sum_y[gi] -
              (double)lamuda[gi] * inva;
      ((e & 1) ? n1 : n0) += tv[e] * tv[e];
    }
    double nsq = wave_sum_d(n0 + n1);
    double nn = sqrt(nsq);
    double ee = sqrt((double)Nq * (double)var_p[0]);
    double scale = (nn > ee) ? ee / fmax(nn, 1e-30) : 1.0;
    if (tid == 0) sh_scale_d = scale;
    double oms = 1.0 - scale;  // resid = tv*(1-scale) + xm*cos + ym*sin
#pragma unroll
    for (int e = 0; e < NL; ++e) tv[e] *= oms;
  }

  // ---- eIF cumtrapz phase + trig + per-system build ----
  const double dx = 1.0 / (double)fs_p[0];
  const double c0 = PI_D * dx;
  float dd[NL], r[NL], x[NL];
  {
    double ev[NL], pl[NL];
#pragma unroll
    for (int e = 0; e < NL; ++e) ev[e] = (double)eIF[base + lane * NL + e];
    pl[0] = ev[0];
#pragma unroll
    for (int e = 1; e < NL; ++e) pl[e] = pl[e - 1] + ev[e];
    double offs = lane_excl_prefix_d(pl[NL - 1], lane);
    double y0 = __shfl(ev[0], 0, 64);
#pragma unroll
    for (int e = 0; e < NL; ++e) {
      int i = lane * NL + e;
      double ph = c0 * (2.0 * (offs + pl[e]) - ev[e] - y0);  // 2*pi*cumtrapz
      float sn, cs;
      fast_sincos_ph(ph, &sn, &cs);
      float xmv = xm[base + i], ymv = ym[base + i];
      double resid = tv[e] + (double)xmv * (double)cs + (double)ymv * (double)sn;
      if (syst == 0) {
        dd[e] = cs * cs + 1e-6f;
        r[e] = (float)((double)cs * resid);
        x[e] = xmv;
      } else {
        dd[e] = sn * sn + 1e-6f;
        r[e] = (float)((double)sn * resid);
        x[e] = ymv;
      }
    }
  }

  // ---- CG: X-wave solves X system, Y-wave solves Y system (zero barriers) --
  cg_wave_f<false>(coefA, dd, r, x, lane);

  // publish xs/ys for own row
  {
    float* dst = (syst == 0) ? sh_xs[rr] : sh_ys[rr];
#pragma unroll
    for (int e = 0; e < NL; ++e) dst[e * 64 + lane] = x[e];
  }
  __syncthreads();

  // ---- deltaIF (both waves of a row identically) ----
  {
    float xs[NL], ys[NL];
#pragma unroll
    for (int e = 0; e < NL; ++e) {
      xs[e] = sh_xs[rr][e * 64 + lane];
      ys[e] = sh_ys[rr][e * 64 + lane];
    }
    float invdx = (float)fs_p[0], inv2dx = 0.5f * invdx;
    float xl = __shfl_up(xs[NL - 1], 1, 64), xr = __shfl_down(xs[0], 1, 64);
    float yl = __shfl_up(ys[NL - 1], 1, 64), yr = __shfl_down(ys[0], 1, 64);
#pragma unroll
    for (int e = 0; e < NL; ++e) {
      int i = lane * NL + e;
      float xm1 = (e >= 1) ? xs[e - 1] : xl;
      float xp1 = (e <= NL - 2) ? xs[e + 1] : xr;
      float ym1 = (e >= 1) ? ys[e - 1] : yl;
      float yp1 = (e <= NL - 2) ? ys[e + 1] : yr;
      float xb, yb;
      if (i == 0) {
        xb = (xp1 - xs[e]) * invdx;
        yb = (yp1 - ys[e]) * invdx;
      } else if (i == Nq - 1) {
        xb = (xs[e] - xm1) * invdx;
        yb = (ys[e] - ym1) * invdx;
      } else {
        xb = (xp1 - xm1) * inv2dx;
        yb = (yp1 - ym1) * inv2dx;
      }
      float denom = xs[e] * xs[e] + ys[e] * ys[e] + 1e-12f;
      r[e] = (xs[e] * yb - ys[e] * xb) / (denom * (float)TWO_PI_D);
      x[e] = 0.0f;
    }
  }

  // ---- smooth CG (both waves of a row redundantly; identical result) ----
  cg_wave_f<true>(coefS, nullptr, r, x, lane);

  // ---- epilogue: outputs + new-phase contributions ----
  bool active = mode_mask[row] != 0;
  double eifn[NL], pl[NL];
#pragma unroll
  for (int e = 0; e < NL; ++e) {
    int i = base + lane * NL + e;
    double eifv = (double)eIF[i];
    eifn[e] = active ? (eifv - 0.5 * (double)x[e]) : eifv;
  }
  if (syst == 0) {
#pragma unroll
    for (int e = 0; e < NL; ++e) {
      int i = base + lane * NL + e;
      out_eIF[i] = (float)eifn[e];
      out_xm[i] = active ? sh_xs[rr][e * 64 + lane] : xm[i];
    }
  } else {
#pragma unroll
    for (int e = 0; e < NL; ++e) {
      int i = base + lane * NL + e;
      out_ym[i] = active ? sh_ys[rr][e * 64 + lane] : ym[i];
    }
  }
  pl[0] = eifn[0];
#pragma unroll
  for (int e = 1; e < NL; ++e) pl[e] = pl[e - 1] + eifn[e];
  double offs = lane_excl_prefix_d(pl[NL - 1], lane);
  double y0 = __shfl(eifn[0], 0, 64);
  if (active) {
#pragma unroll
    for (int e = 0; e < NL; ++e) {
      int i = lane * NL + e;
      double ph = c0 * (2.0 * (offs + pl[e]) - eifn[e] - y0);
      float sn, cs;
      fast_sincos_ph(ph, &sn, &cs);
      if (syst == 0)
        atomicAdd(&sh_bsx[i], sh_xs[rr][e * 64 + lane] * cs);
      else
        atomicAdd(&sh_bsy[i], sh_ys[rr][e * 64 + lane] * sn);
    }
  }
  __syncthreads();

  // ---- final: bsx/bsy + u + new lamuda (folded) ----
  {
    double na = sh_hdr[0];
    double scale = sh_scale_d;
#pragma unroll
    for (int j = 0; j < 4; ++j) {
      int i = tid + j * 512;
      int gi = bb + i;
      double t = (double)s[gi] - (double)sum_x[gi] - (double)sum_y[gi] -
                 (double)lamuda[gi] * inva;
      double u = t * scale;
      double bx = (double)sh_bsx[i], by = (double)sh_bsy[i];
      double nl = (double)lamuda[gi] + na * (u + bx + by - (double)s[gi]);
      out_bsx[gi] = (float)bx;
      out_bsy[gi] = (float)by;
      out_lam[gi] = (float)nl;
    }
  }
}

// ---------------- launcher ----------------
extern "C" void kernel_launch(void* const* d_in, const int* in_sizes, int n_in,
                              void* d_out, int out_size, void* d_ws, size_t ws_size,
                              hipStream_t stream) {
  (void)in_sizes; (void)n_in; (void)out_size; (void)d_ws; (void)ws_size;
  const float* s = (const float*)d_in[0];
  const float* eIF = (const float*)d_in[1];
  const float* xm = (const float*)d_in[2];
  const float* ym = (const float*)d_in[3];
  const float* sum_x = (const float*)d_in[4];
  const float* sum_y = (const float*)d_in[5];
  const float* lamuda = (const float*)d_in[6];
  const float* init_freqs = (const float*)d_in[7];
  const int* mode_mask = (const int*)d_in[8];
  const float* alpha = (const float*)d_in[9];
  const float* beta = (const float*)d_in[10];
  const float* var = (const float*)d_in[11];
  const float* fs = (const float*)d_in[12];
  const int* iteration = (const int*)d_in[13];
  const float* fe_w1 = (const float*)d_in[14];
  const float* fe_b1 = (const float*)d_in[15];
  const float* fe_w2 = (const float*)d_in[16];
  const float* fe_b2 = (const float*)d_in[17];
  const float* pr_w1 = (const float*)d_in[18];
  const float* pr_b1 = (const float*)d_in[19];
  const float* pr_w2 = (const float*)d_in[20];
  const float* pr_b2 = (const float*)d_in[21];
  const float* pr_w3 = (const float*)d_in[22];
  const float* pr_b3 = (const float*)d_in[23];
  const float* iter_weight = (const float*)d_in[24];

  float* out = (float*)d_out;
  const int BN = Bq * Nq;  // 16384
  const int BKN = 4 * BN;  // 65536
  float* out_eIF = out;
  float* out_xm = out + BKN;
  float* out_ym = out + 2 * BKN;
  float* out_bsx = out + 3 * BKN;
  float* out_bsy = out + 3 * BKN + BN;
  float* out_lam = out + 3 * BKN + 2 * BN;
  float* out_scal = out + 3 * BKN + 3 * BN;  // [new_alpha, new_beta]

  mega_kernel<<<Bq, 512, 0, stream>>>(
      s, eIF, xm, ym, sum_x, sum_y, lamuda, init_freqs, mode_mask, alpha, beta,
      var, fs, iteration, fe_w1, fe_b1, fe_w2, fe_b2, pr_w1, pr_b1, pr_w2,
      pr_b2, pr_w3, pr_b3, iter_weight, out_eIF, out_xm, out_ym, out_bsx,
      out_bsy, out_lam, out_scal);
}

// Round 10
// 231.896 us; speedup vs baseline: 1.4004x; 1.0037x over previous
//
#include <hip/hip_runtime.h>
#include <math.h>

#define Nq 2048
#define Bq 8
#define Kq 4
#define NL 32  // elements per lane (2048 / 64)
#define TWO_PI_D 6.283185307179586
#define PI_D 3.141592653589793
#define INV2PI_D 0.15915494309189535

// ---------------- wave helpers ----------------

__device__ __forceinline__ double wave_sum_d(double v) {
#pragma unroll
  for (int off = 1; off < 64; off <<= 1) v += __shfl_xor(v, off, 64);
  return v;
}

// Canonical GCN DPP wave64 sum; uniform result via readlane 63.
__device__ __forceinline__ float dpp_sum_f32(float v) {
  v += __int_as_float(__builtin_amdgcn_update_dpp(0, __float_as_int(v), 0x111, 0xf, 0xf, false));  // row_shr:1
  v += __int_as_float(__builtin_amdgcn_update_dpp(0, __float_as_int(v), 0x112, 0xf, 0xf, false));  // row_shr:2
  v += __int_as_float(__builtin_amdgcn_update_dpp(0, __float_as_int(v), 0x114, 0xf, 0xe, false));  // row_shr:4
  v += __int_as_float(__builtin_amdgcn_update_dpp(0, __float_as_int(v), 0x118, 0xf, 0xc, false));  // row_shr:8
  v += __int_as_float(__builtin_amdgcn_update_dpp(0, __float_as_int(v), 0x142, 0xa, 0xf, false));  // row_bcast:15
  v += __int_as_float(__builtin_amdgcn_update_dpp(0, __float_as_int(v), 0x143, 0xc, 0xf, false));  // row_bcast:31
  return __int_as_float(__builtin_amdgcn_readlane(__float_as_int(v), 63));
}

__device__ __forceinline__ float dpp_up1(float v) {  // lane i <- lane i-1
  return __int_as_float(__builtin_amdgcn_update_dpp(0, __float_as_int(v), 0x138, 0xf, 0xf, false));  // wave_shr:1
}
__device__ __forceinline__ float dpp_dn1(float v) {  // lane i <- lane i+1
  return __int_as_float(__builtin_amdgcn_update_dpp(0, __float_as_int(v), 0x130, 0xf, 0xf, false));  // wave_shl:1
}

__device__ __forceinline__ double lane_excl_prefix_d(double T, int lane) {
  double acc = T;
#pragma unroll
  for (int off = 1; off < 64; off <<= 1) {
    double t = __shfl_up(acc, off, 64);
    if (lane >= off) acc += t;
  }
  return acc - T;
}

__device__ __forceinline__ void fast_sincos_ph(double ph, float* sn, float* cs) {
  double k = trunc(ph * INV2PI_D);
  float phr = (float)(ph - k * TWO_PI_D);
  __sincosf(phr, sn, cs);
}

// Full matvec Ap = (coef*opedoub + diag(de)) p, with dd[e] = 6*coef + de[e]
// folded in. Endpoint rows (global 0,1,N-2,N-1) fixed up on lanes 0/63.
template <bool UNIT>
__device__ __forceinline__ void applyA(const float* p, float* Ap,
                                       const float* dd, float c, float c3,
                                       float c4, float ddu, int lane) {
  float lm1 = dpp_up1(p[NL - 1]);
  float lm2 = dpp_up1(p[NL - 2]);
  float rp1 = dpp_dn1(p[0]);
  float rp2 = dpp_dn1(p[1]);
#pragma unroll
  for (int e = 0; e < NL; ++e) {
    float m2 = (e >= 2) ? p[e - 2] : (e == 1 ? lm1 : lm2);
    float m1 = (e >= 1) ? p[e - 1] : lm1;
    float q1 = (e <= NL - 2) ? p[e + 1] : rp1;
    float q2 = (e <= NL - 3) ? p[e + 2] : (e == NL - 2 ? rp1 : rp2);
    float t1 = m2 + q2, t2 = m1 + q1;
    float u = fmaf(c, t1, -(c4 * t2));
    float d = UNIT ? ddu : dd[e];
    Ap[e] = fmaf(d, p[e], u);
  }
  if (lane == 0) {
    float d0 = (UNIT ? ddu : dd[0]) - c4;  // = 2c + de0
    Ap[0] = fmaf(d0, p[0], fmaf(c, p[2], -(c3 * p[1])));
    float d1 = UNIT ? ddu : dd[1];
    Ap[1] = fmaf(d1, p[1], -(c3 * p[0])) + fmaf(c, p[3], -(c4 * p[2]));
  }
  if (lane == 63) {
    float dm2 = UNIT ? ddu : dd[NL - 2];
    Ap[NL - 2] = fmaf(dm2, p[NL - 2], c * p[NL - 4]) -
                 fmaf(c4, p[NL - 3], c3 * p[NL - 1]);
    float dm1 = (UNIT ? ddu : dd[NL - 1]) - c4;  // = 2c + de
    Ap[NL - 1] = fmaf(dm1, p[NL - 1], c * p[NL - 3]) - c3 * p[NL - 2];
  }
}

// Wave CG (f32 state, zero barriers) on (coef*opedoub + diag(de)) z = rhs.
// de passed in dd[] (or unit diag); dd is destructively updated to 6c+de.
// In: x = x0, r = rhs. Out: x = solution. Reference freeze semantics.
template <bool UNIT>
__device__ __forceinline__ void cg_wave_f(float coef, float* dd, float* r,
                                          float* x, int lane) {
  const float c = coef, c3 = 3.0f * coef, c4 = 4.0f * coef;
  const float ddu = 6.0f * coef + (1.0f + 1e-6f);
  if (!UNIT) {
#pragma unroll
    for (int e = 0; e < NL; ++e) dd[e] += 6.0f * coef;
  }
  float p[NL], Ap[NL];
  applyA<UNIT>(x, Ap, dd, c, c3, c4, ddu, lane);
  float s0 = 0, s1 = 0, s2 = 0, s3 = 0;
#pragma unroll
  for (int e = 0; e < NL; ++e) {
    r[e] -= Ap[e];
    p[e] = r[e];
    float* acc = (e & 2) ? ((e & 1) ? &s3 : &s2) : ((e & 1) ? &s1 : &s0);
    *acc = fmaf(r[e], r[e], *acc);
  }
  float rsold = dpp_sum_f32((s0 + s1) + (s2 + s3));
  for (int it = 0; it < 30; ++it) {
    applyA<UNIT>(p, Ap, dd, c, c3, c4, ddu, lane);
    float d0 = 0, d1 = 0, d2 = 0, d3 = 0;
#pragma unroll
    for (int e = 0; e < NL; ++e) {
      float* acc = (e & 2) ? ((e & 1) ? &d3 : &d2) : ((e & 1) ? &d1 : &d0);
      *acc = fmaf(p[e], Ap[e], *acc);
    }
    float pap = dpp_sum_f32((d0 + d1) + (d2 + d3));
    float a = __fdividef(rsold, pap + 1e-12f);
    float t0 = 0, t1 = 0, t2 = 0, t3 = 0;
#pragma unroll
    for (int e = 0; e < NL; ++e) {
      x[e] = fmaf(a, p[e], x[e]);
      r[e] = fmaf(-a, Ap[e], r[e]);
      float* acc = (e & 2) ? ((e & 1) ? &t3 : &t2) : ((e & 1) ? &t1 : &t0);
      *acc = fmaf(r[e], r[e], *acc);
    }
    float rsnew = dpp_sum_f32((t0 + t1) + (t2 + t3));
    if (rsnew < 1e-12f) break;  // == sqrt(rsnew) < 1e-6 (monotone)
    float bta = __fdividef(rsnew, rsold + 1e-12f);
#pragma unroll
    for (int e = 0; e < NL; ++e) p[e] = fmaf(bta, p[e], r[e]);
    rsold = rsnew;
  }
}

// ---- mega kernel: 1 block per batch b; 8 waves = 4 rows x {X,Y} ----
// wave w: rr = w>>1 (row-in-batch), syst = w&1 (0=X, 1=Y). Each wave runs a
// full-row zero-barrier CG; 2 waves/SIMD co-resident for latency hiding.
// amdgpu_waves_per_eu(2,2): LDS (91.6 KB) already limits us to 1 block/CU
// = 2 waves/SIMD; cap the allocator's occupancy target so it uses the full
// 256-reg budget instead of spilling at 128 (R9: 1.2 MB scratch writes).
__global__ __attribute__((amdgpu_flat_work_group_size(512, 512),
                          amdgpu_waves_per_eu(2, 2))) void mega_kernel(
    const float* __restrict__ s, const float* __restrict__ eIF,
    const float* __restrict__ xm, const float* __restrict__ ym,
    const float* __restrict__ sum_x, const float* __restrict__ sum_y,
    const float* __restrict__ lamuda, const float* __restrict__ init_freqs,
    const int* __restrict__ mode_mask, const float* __restrict__ alpha_p,
    const float* __restrict__ beta_p, const float* __restrict__ var_p,
    const float* __restrict__ fs_p, const int* __restrict__ iter_p,
    const float* __restrict__ fe_w1, const float* __restrict__ fe_b1,
    const float* __restrict__ fe_w2, const float* __restrict__ fe_b2,
    const float* __restrict__ pr_w1, const float* __restrict__ pr_b1,
    const float* __restrict__ pr_w2, const float* __restrict__ pr_b2,
    const float* __restrict__ pr_w3, const float* __restrict__ pr_b3,
    const float* __restrict__ iter_w_p, float* __restrict__ out_eIF,
    float* __restrict__ out_xm, float* __restrict__ out_ym,
    float* __restrict__ out_bsx, float* __restrict__ out_bsy,
    float* __restrict__ out_lam, float* __restrict__ out_scal) {
  __shared__ double sh_avg[Bq];
  __shared__ double sh_h1[Bq][32];
  __shared__ double sh_zz[Bq][18];
  __shared__ double sh_z1[Bq][64];
  __shared__ double sh_z2[Bq][32];
  __shared__ double sh_res[Bq][2];
  __shared__ double sh_hdr[4];
  __shared__ double sh_scale_d;
  __shared__ float sh_xs[Kq][Nq], sh_ys[Kq][Nq];
  __shared__ float sh_bsx[Nq], sh_bsy[Nq];

  const int tid = threadIdx.x;
  const int wv = tid >> 6, lane = tid & 63;
  const int rr = wv >> 1, syst = wv & 1;
  const int b = blockIdx.x;
  const int row = b * Kq + rr;
  const int bb = b * Nq, base = row * Nq;

  for (int j = tid; j < Nq; j += 512) {
    sh_bsx[j] = 0.f;
    sh_bsy[j] = 0.f;
  }

  // ---- hyperparameter MLP (once per block, f64 deterministic) ----
  double alpha = (double)alpha_p[0], beta = (double)beta_p[0];
  double iterv = (double)iter_p[0];
  if (tid < Bq) {
    double avg = 0.0;
#pragma unroll
    for (int k = 0; k < Kq; ++k) avg += (double)init_freqs[tid * Kq + k];
    sh_avg[tid] = avg * (1.0 / Kq);
  }
  __syncthreads();
  if (tid < 256) {
    int b2 = tid >> 5, j = tid & 31;
    double v = (double)fe_w1[j] * sh_avg[b2] + (double)fe_b1[j];
    sh_h1[b2][j] = v > 0.0 ? v : 0.0;
  }
  __syncthreads();
  if (tid < 128) {
    int b2 = tid >> 4, j = tid & 15;
    double acc = (double)fe_b2[j];
    for (int i = 0; i < 32; ++i) acc += (double)fe_w2[j * 32 + i] * sh_h1[b2][i];
    sh_zz[b2][j] = acc > 0.0 ? acc : 0.0;
  }
  if (tid >= 128 && tid < 128 + Bq) {
    sh_zz[tid - 128][16] = alpha;
    sh_zz[tid - 128][17] = beta;
  }
  __syncthreads();
  {
    int b2 = tid >> 6, j = tid & 63;
    double acc = (double)pr_b1[j];
    for (int i = 0; i < 18; ++i) acc += (double)pr_w1[j * 18 + i] * sh_zz[b2][i];
    sh_z1[b2][j] = acc > 0.0 ? acc : 0.0;
  }
  __syncthreads();
  if (tid < 256) {
    int b2 = tid >> 5, j = tid & 31;
    double acc = (double)pr_b2[j];
    for (int i = 0; i < 64; ++i) acc += (double)pr_w2[j * 64 + i] * sh_z1[b2][i];
    sh_z2[b2][j] = acc > 0.0 ? acc : 0.0;
  }
  __syncthreads();
  if (tid < 16) {
    int b2 = tid >> 1, c = tid & 1;
    double acc = (double)pr_b3[c];
    for (int i = 0; i < 32; ++i) acc += (double)pr_w3[c * 32 + i] * sh_z2[b2][i];
    double fac = 1.0 / (1.0 + exp(-(double)iter_w_p[0] * iterv));
    sh_res[b2][c] = tanh(acc) * fac * 0.1;
  }
  __syncthreads();
  if (tid == 0) {
    double r0 = 0.0, r1 = 0.0;
    for (int q = 0; q < Bq; ++q) { r0 += sh_res[q][0]; r1 += sh_res[q][1]; }
    double na = fmin(fmax(alpha + r0 * alpha * (1.0 / Bq), 1e-6), 0.01);
    double nb2 = fmin(fmax(beta + r1 * beta * (1.0 / Bq), 1e-6), 0.1);
    double betathr = fmin(pow(10.0, iterv / 36.0 - 10.0), nb2);
    sh_hdr[0] = na;
    sh_hdr[1] = 2.0 / na;       // coefA
    sh_hdr[2] = 2.0 / betathr;  // coefS
    sh_hdr[3] = 1.0 / na;       // inv_alpha
    if (b == 0) {
      out_scal[0] = (float)na;
      out_scal[1] = (float)nb2;
    }
  }
  __syncthreads();
  const float coefA = (float)sh_hdr[1];
  const float coefS = (float)sh_hdr[2];
  const double inva = sh_hdr[3];

  // ---- u scale for batch b (per-wave redundant, f64) ----
  double tv[NL];
  {
    double n0 = 0.0, n1 = 0.0;
#pragma unroll
    for (int e = 0; e < NL; ++e) {
      int gi = bb + lane * NL + e;
      tv[e] = (double)s[gi] - (double)sum_x[gi] - (double)sum_y[gi] -
              (double)lamuda[gi] * inva;
      ((e & 1) ? n1 : n0) += tv[e] * tv[e];
    }
    double nsq = wave_sum_d(n0 + n1);
    double nn = sqrt(nsq);
    double ee = sqrt((double)Nq * (double)var_p[0]);
    double scale = (nn > ee) ? ee / fmax(nn, 1e-30) : 1.0;
    if (tid == 0) sh_scale_d = scale;
    double oms = 1.0 - scale;  // resid = tv*(1-scale) + xm*cos + ym*sin
#pragma unroll
    for (int e = 0; e < NL; ++e) tv[e] *= oms;
  }

  // ---- eIF cumtrapz phase + trig + per-system build ----
  const double dx = 1.0 / (double)fs_p[0];
  const double c0 = PI_D * dx;
  float dd[NL], r[NL], x[NL];
  {
    double ev[NL], pl[NL];
#pragma unroll
    for (int e = 0; e < NL; ++e) ev[e] = (double)eIF[base + lane * NL + e];
    pl[0] = ev[0];
#pragma unroll
    for (int e = 1; e < NL; ++e) pl[e] = pl[e - 1] + ev[e];
    double offs = lane_excl_prefix_d(pl[NL - 1], lane);
    double y0 = __shfl(ev[0], 0, 64);
#pragma unroll
    for (int e = 0; e < NL; ++e) {
      int i = lane * NL + e;
      double ph = c0 * (2.0 * (offs + pl[e]) - ev[e] - y0);  // 2*pi*cumtrapz
      float sn, cs;
      fast_sincos_ph(ph, &sn, &cs);
      float xmv = xm[base + i], ymv = ym[base + i];
      double resid = tv[e] + (double)xmv * (double)cs + (double)ymv * (double)sn;
      if (syst == 0) {
        dd[e] = cs * cs + 1e-6f;
        r[e] = (float)((double)cs * resid);
        x[e] = xmv;
      } else {
        dd[e] = sn * sn + 1e-6f;
        r[e] = (float)((double)sn * resid);
        x[e] = ymv;
      }
    }
  }

  // ---- CG: X-wave solves X system, Y-wave solves Y system (zero barriers) --
  cg_wave_f<false>(coefA, dd, r, x, lane);

  // publish xs/ys for own row
  {
    float* dst = (syst == 0) ? sh_xs[rr] : sh_ys[rr];
#pragma unroll
    for (int e = 0; e < NL; ++e) dst[e * 64 + lane] = x[e];
  }
  __syncthreads();

  // ---- deltaIF (both waves of a row identically) ----
  {
    float xs[NL], ys[NL];
#pragma unroll
    for (int e = 0; e < NL; ++e) {
      xs[e] = sh_xs[rr][e * 64 + lane];
      ys[e] = sh_ys[rr][e * 64 + lane];
    }
    float invdx = (float)fs_p[0], inv2dx = 0.5f * invdx;
    float xl = __shfl_up(xs[NL - 1], 1, 64), xr = __shfl_down(xs[0], 1, 64);
    float yl = __shfl_up(ys[NL - 1], 1, 64), yr = __shfl_down(ys[0], 1, 64);
#pragma unroll
    for (int e = 0; e < NL; ++e) {
      int i = lane * NL + e;
      float xm1 = (e >= 1) ? xs[e - 1] : xl;
      float xp1 = (e <= NL - 2) ? xs[e + 1] : xr;
      float ym1 = (e >= 1) ? ys[e - 1] : yl;
      float yp1 = (e <= NL - 2) ? ys[e + 1] : yr;
      float xb, yb;
      if (i == 0) {
        xb = (xp1 - xs[e]) * invdx;
        yb = (yp1 - ys[e]) * invdx;
      } else if (i == Nq - 1) {
        xb = (xs[e] - xm1) * invdx;
        yb = (ys[e] - ym1) * invdx;
      } else {
        xb = (xp1 - xm1) * inv2dx;
        yb = (yp1 - ym1) * inv2dx;
      }
      float denom = xs[e] * xs[e] + ys[e] * ys[e] + 1e-12f;
      r[e] = (xs[e] * yb - ys[e] * xb) / (denom * (float)TWO_PI_D);
      x[e] = 0.0f;
    }
  }

  // ---- smooth CG (both waves of a row redundantly; identical result) ----
  cg_wave_f<true>(coefS, nullptr, r, x, lane);

  // ---- epilogue: outputs + new-phase contributions ----
  bool active = mode_mask[row] != 0;
  double eifn[NL], pl[NL];
#pragma unroll
  for (int e = 0; e < NL; ++e) {
    int i = base + lane * NL + e;
    double eifv = (double)eIF[i];
    eifn[e] = active ? (eifv - 0.5 * (double)x[e]) : eifv;
  }
  if (syst == 0) {
#pragma unroll
    for (int e = 0; e < NL; ++e) {
      int i = base + lane * NL + e;
      out_eIF[i] = (float)eifn[e];
      out_xm[i] = active ? sh_xs[rr][e * 64 + lane] : xm[i];
    }
  } else {
#pragma unroll
    for (int e = 0; e < NL; ++e) {
      int i = base + lane * NL + e;
      out_ym[i] = active ? sh_ys[rr][e * 64 + lane] : ym[i];
    }
  }
  pl[0] = eifn[0];
#pragma unroll
  for (int e = 1; e < NL; ++e) pl[e] = pl[e - 1] + eifn[e];
  double offs = lane_excl_prefix_d(pl[NL - 1], lane);
  double y0 = __shfl(eifn[0], 0, 64);
  if (active) {
#pragma unroll
    for (int e = 0; e < NL; ++e) {
      int i = lane * NL + e;
      double ph = c0 * (2.0 * (offs + pl[e]) - eifn[e] - y0);
      float sn, cs;
      fast_sincos_ph(ph, &sn, &cs);
      if (syst == 0)
        atomicAdd(&sh_bsx[i], sh_xs[rr][e * 64 + lane] * cs);
      else
        atomicAdd(&sh_bsy[i], sh_ys[rr][e * 64 + lane] * sn);
    }
  }
  __syncthreads();

  // ---- final: bsx/bsy + u + new lamuda (folded) ----
  {
    double na = sh_hdr[0];
    double scale = sh_scale_d;
#pragma unroll
    for (int j = 0; j < 4; ++j) {
      int i = tid + j * 512;
      int gi = bb + i;
      double t = (double)s[gi] - (double)sum_x[gi] - (double)sum_y[gi] -
                 (double)lamuda[gi] * inva;
      double u = t * scale;
      double bx = (double)sh_bsx[i], by = (double)sh_bsy[i];
      double nl = (double)lamuda[gi] + na * (u + bx + by - (double)s[gi]);
      out_bsx[gi] = (float)bx;
      out_bsy[gi] = (float)by;
      out_lam[gi] = (float)nl;
    }
  }
}

// ---------------- launcher ----------------
extern "C" void kernel_launch(void* const* d_in, const int* in_sizes, int n_in,
                              void* d_out, int out_size, void* d_ws, size_t ws_size,
                              hipStream_t stream) {
  (void)in_sizes; (void)n_in; (void)out_size; (void)d_ws; (void)ws_size;
  const float* s = (const float*)d_in[0];
  const float* eIF = (const float*)d_in[1];
  const float* xm = (const float*)d_in[2];
  const float* ym = (const float*)d_in[3];
  const float* sum_x = (const float*)d_in[4];
  const float* sum_y = (const float*)d_in[5];
  const float* lamuda = (const float*)d_in[6];
  const float* init_freqs = (const float*)d_in[7];
  const int* mode_mask = (const int*)d_in[8];
  const float* alpha = (const float*)d_in[9];
  const float* beta = (const float*)d_in[10];
  const float* var = (const float*)d_in[11];
  const float* fs = (const float*)d_in[12];
  const int* iteration = (const int*)d_in[13];
  const float* fe_w1 = (const float*)d_in[14];
  const float* fe_b1 = (const float*)d_in[15];
  const float* fe_w2 = (const float*)d_in[16];
  const float* fe_b2 = (const float*)d_in[17];
  const float* pr_w1 = (const float*)d_in[18];
  const float* pr_b1 = (const float*)d_in[19];
  const float* pr_w2 = (const float*)d_in[20];
  const float* pr_b2 = (const float*)d_in[21];
  const float* pr_w3 = (const float*)d_in[22];
  const float* pr_b3 = (const float*)d_in[23];
  const float* iter_weight = (const float*)d_in[24];

  float* out = (float*)d_out;
  const int BN = Bq * Nq;  // 16384
  const int BKN = 4 * BN;  // 65536
  float* out_eIF = out;
  float* out_xm = out + BKN;
  float* out_ym = out + 2 * BKN;
  float* out_bsx = out + 3 * BKN;
  float* out_bsy = out + 3 * BKN + BN;
  float* out_lam = out + 3 * BKN + 2 * BN;
  float* out_scal = out + 3 * BKN + 3 * BN;  // [new_alpha, new_beta]

  mega_kernel<<<Bq, 512, 0, stream>>>(
      s, eIF, xm, ym, sum_x, sum_y, lamuda, init_freqs, mode_mask, alpha, beta,
      var, fs, iteration, fe_w1, fe_b1, fe_w2, fe_b2, pr_w1, pr_b1, pr_w2,
      pr_b2, pr_w3, pr_b3, iter_weight, out_eIF, out_xm, out_ym, out_bsx,
      out_bsy, out_lam, out_scal);
}